// Round 2
// baseline (320.209 us; speedup 1.0000x reference)
//
#include <hip/hip_runtime.h>

#define B_ 16
#define N_ 16384
#define K_ 16

// ---- workspace layout (float offsets) ----
enum : int {
  WS_LAT  = 0,      // 32 x 128 latent (f32, atomicMax-as-uint, relu>=0)
  WS_SEL  = 5632,   // 32 x 48 selected keypoints
  WS_PMIN = 7168,   // 16 x 3 (ordered-uint encoded)
  WS_PMAX = 7216,   // 16 x 3 (ordered-uint encoded)
  WS_CF   = 7264,   // 16 x 512 x 3 cage corners
  WS_W1F  = 31840,  // 64 x 3  bn-folded (fp32)
  WS_B1F  = 32032,  // 64
  // split-f16 B-fragment tables (MFMA layout), built by prep:
  WS_WB2H = 32096,  // 8192 f16 (4096 floats): layer2 B hi frags [nt*2+kt][lane][8]
  WS_WB2L = 36192,  // 8192 f16
  WS_B2F  = 40288,  // 128 fp32 folded bias
  WS_WB3H = 40416,  // 32768 f16 (16384 floats): layer3 B hi frags [nt*4+kt][lane][8]
  WS_B3F  = 56800,  // 128 fp32 folded bias
  WS_WB3L = 56928,  // 32768 f16 (16384 floats)
  WS_END  = 73312
};

enum : int { OUT_DEF=0, OUT_SRCKP=786432, OUT_TGTKP=787200 };

typedef _Float16 f16x8 __attribute__((ext_vector_type(8)));
typedef _Float16 f16x2 __attribute__((ext_vector_type(2)));
typedef float    f32x4 __attribute__((ext_vector_type(4)));

__device__ __forceinline__ float dist2rn(float px,float py,float pz,float sx,float sy,float sz){
  float dx=__fsub_rn(px,sx), dy=__fsub_rn(py,sy), dz=__fsub_rn(pz,sz);
  return __fadd_rn(__fadd_rn(__fmul_rn(dx,dx),__fmul_rn(dy,dy)),__fmul_rn(dz,dz));
}

// ordered-uint encoding: monotone bijection float-order -> uint-order
__device__ __forceinline__ unsigned enc_ord(float x){
  unsigned u = __float_as_uint(x);
  return (u & 0x80000000u) ? ~u : (u | 0x80000000u);
}
__device__ __forceinline__ float dec_ord(unsigned e){
  return __uint_as_float((e & 0x80000000u) ? (e & 0x7fffffffu) : ~e);
}

// ---------------- prep: fold BN into encoder weights + split-f16 frags --------
struct EncW {
  const float *w1,*b1,*g1,*be1,*m1,*v1;
  const float *w2,*b2,*g2,*be2,*m2,*v2;
  const float *w3,*b3,*g3,*be3,*m3,*v3;
};

__device__ __forceinline__ float bn_scale(const float* g, const float* v, int ch){
  return g[ch] * (1.0f / sqrtf(v[ch] + 1e-5f));
}

__global__ void prep_kernel(EncW a, float* ws){
  const int stride = gridDim.x*blockDim.x;
  const int tid = blockIdx.x*blockDim.x + threadIdx.x;
  for (int i=tid;i<4096;i+=stride)            // zero latent (atomicMax target)
    ws[WS_LAT+i] = 0.0f;
  for (int i=tid;i<48;i+=stride){             // init min/max atomic targets
    ((unsigned*)ws)[WS_PMIN+i] = 0xFFFFFFFFu;
    ((unsigned*)ws)[WS_PMAX+i] = 0u;
  }
  for (int i=tid;i<192;i+=stride){            // W1F (fp32: layer1 stays on VALU)
    int o=i/3;
    ws[WS_W1F+i] = a.w1[i] * bn_scale(a.g1,a.v1,o);
  }
  for (int i=tid;i<64;i+=stride){             // B1F
    float s = bn_scale(a.g1,a.v1,i);
    ws[WS_B1F+i] = (a.b1[i] - a.m1[i])*s + a.be1[i];
  }
  // layer2 B-frags, split f16 hi/lo. frag layout: lane l of MFMA B operand holds
  // B[k = kt*32 + (l>>4)*8 + j][col = nt*16 + (l&15)], j=0..7 contiguous.
  for (int i=tid;i<8192;i+=stride){
    int j = i & 7, frag = i >> 3;
    int l = frag & 63, nk = frag >> 6;        // nk = nt*2 + kt
    int kt = nk & 1, nt = nk >> 1;
    int c = kt*32 + ((l>>4)<<3) + j;          // 0..63 in-channel (K)
    int o = nt*16 + (l&15);                   // 0..127 out-channel (N)
    float v = a.w2[o*64+c] * bn_scale(a.g2,a.v2,o);
    _Float16 h = (_Float16)v;
    ((_Float16*)(ws+WS_WB2H))[i] = h;
    ((_Float16*)(ws+WS_WB2L))[i] = (_Float16)(v - (float)h);
  }
  for (int i=tid;i<128;i+=stride){
    float s = bn_scale(a.g2,a.v2,i);
    ws[WS_B2F+i] = (a.b2[i] - a.m2[i])*s + a.be2[i];
  }
  // layer3 B-frags, split f16 hi/lo
  for (int i=tid;i<32768;i+=stride){
    int j = i & 7, frag = i >> 3;
    int l = frag & 63, nk = frag >> 6;        // nk = nt*4 + kt
    int kt = nk & 3, nt = nk >> 2;
    int c = kt*32 + ((l>>4)<<3) + j;          // 0..127 in-channel (K)
    int o = nt*16 + (l&15);                   // 0..127 out-channel (N)
    float v = a.w3[o*128+c] * bn_scale(a.g3,a.v3,o);
    _Float16 h = (_Float16)v;
    ((_Float16*)(ws+WS_WB3H))[i] = h;
    ((_Float16*)(ws+WS_WB3L))[i] = (_Float16)(v - (float)h);
  }
  for (int i=tid;i<128;i+=stride){
    float s = bn_scale(a.g3,a.v3,i);
    ws[WS_B3F+i] = (a.b3[i] - a.m3[i])*s + a.be3[i];
  }
}

// ---------------- source point min/max (exact, order-independent) -------------
__global__ __launch_bounds__(256) void minmax_kernel(const float* __restrict__ src,
                                                     float* __restrict__ ws){
  const int b = blockIdx.y, c = blockIdx.x, t = threadIdx.x;
  const float4* b4 = (const float4*)(src + (size_t)b*N_*3 + (size_t)c*2048*3 + (size_t)t*24);
  float a[24];
  #pragma unroll
  for (int q=0;q<6;q++){ float4 v=b4[q]; a[q*4]=v.x; a[q*4+1]=v.y; a[q*4+2]=v.z; a[q*4+3]=v.w; }
  float mn[3]={3.4e38f,3.4e38f,3.4e38f}, mx[3]={-3.4e38f,-3.4e38f,-3.4e38f};
  #pragma unroll
  for (int k=0;k<8;k++){
    mn[0]=fminf(mn[0],a[k*3  ]); mx[0]=fmaxf(mx[0],a[k*3  ]);
    mn[1]=fminf(mn[1],a[k*3+1]); mx[1]=fmaxf(mx[1],a[k*3+1]);
    mn[2]=fminf(mn[2],a[k*3+2]); mx[2]=fmaxf(mx[2],a[k*3+2]);
  }
  #pragma unroll
  for (int m=1;m<64;m<<=1){
    #pragma unroll
    for (int cc=0;cc<3;cc++){
      mn[cc]=fminf(mn[cc],__shfl_xor(mn[cc],m,64));
      mx[cc]=fmaxf(mx[cc],__shfl_xor(mx[cc],m,64));
    }
  }
  if ((t&63)==0){
    unsigned* wsu = (unsigned*)ws;
    #pragma unroll
    for (int cc=0;cc<3;cc++){
      atomicMin(&wsu[WS_PMIN + b*3 + cc], enc_ord(mn[cc]));
      atomicMax(&wsu[WS_PMAX + b*3 + cc], enc_ord(mx[cc]));
    }
  }
}

// ---------------- encoder v11: split-f16 MFMA for layers 2+3 (unchanged) ------
__global__ __launch_bounds__(512, 4) void encode_kernel(const float* __restrict__ src,
                                                        const float* __restrict__ tgt,
                                                        const float* __restrict__ ws,
                                                        float* __restrict__ lat){
  const int cloud = blockIdx.y;
  const int tile  = blockIdx.x;              // 128 tiles/cloud, 128 pts each
  const int t = threadIdx.x;
  const int lane = t & 63;
  const int wv = __builtin_amdgcn_readfirstlane(t >> 6);   // 0..7
  const int wm = wv >> 2;                    // 0..1 : rows 64*wm .. +63
  const int wn = wv & 3;                     // 0..3 : cols 32*wn .. +31
  const int lr = lane & 15;                  // row/col within 16x16 tile
  const int lg = lane >> 4;                  // k-group

  __shared__ alignas(16) _Float16 A[32768];  // 64KB
  _Float16* AH1 = A;                         // [128][64]  layer2 input hi
  _Float16* AL1 = A + 8192;                  //            layer2 input lo
  _Float16* AH2 = A;                         // [128][128] layer3 input hi (overlay)
  _Float16* AL2 = A + 16384;                 //            layer3 input lo

  const float* base = ((cloud < B_) ? (src + (size_t)cloud*N_*3)
                                    : (tgt + (size_t)(cloud-B_)*N_*3))
                      + (size_t)tile*128*3;

  // ---- layer 1 (3->64), fp32 VALU: thread t -> point t>>2, channels (t&3)*16..+15
  {
    const int pt = t >> 2, q = t & 3;
    const float x = base[pt*3+0], y = base[pt*3+1], z = base[pt*3+2];
    const float* w1 = ws + WS_W1F;
    const float* b1 = ws + WS_B1F;
    const int swz = (pt & 7) << 3;
    #pragma unroll
    for (int cc = 0; cc < 16; cc += 2){
      const int o = q*16 + cc;
      float v0 = fmaf(w1[o*3+2], z, fmaf(w1[o*3+1], y, w1[o*3+0]*x)) + b1[o];
      float v1 = fmaf(w1[o*3+5], z, fmaf(w1[o*3+4], y, w1[o*3+3]*x)) + b1[o+1];
      v0 = fmaxf(v0, 0.0f); v1 = fmaxf(v1, 0.0f);
      f16x2 h, l;
      h[0] = (_Float16)v0;              h[1] = (_Float16)v1;
      l[0] = (_Float16)(v0 - (float)h[0]); l[1] = (_Float16)(v1 - (float)h[1]);
      const int idx = (pt*64 + o) ^ swz;
      *(f16x2*)&AH1[idx] = h;
      *(f16x2*)&AL1[idx] = l;
    }
  }
  __syncthreads();

  // ---- layer 2 (64->128): M128 K64 N128, 3-term split MFMA
  f32x4 acc2[4][2];
  #pragma unroll
  for (int m=0;m<4;m++){
    #pragma unroll
    for (int n=0;n<2;n++) acc2[m][n] = (f32x4){0.f,0.f,0.f,0.f};
  }
  {
    const _Float16* wb2h = (const _Float16*)(ws + WS_WB2H);
    const _Float16* wb2l = (const _Float16*)(ws + WS_WB2L);
    const int swz = (lr & 7) << 3;
    #pragma unroll
    for (int kt=0; kt<2; kt++){
      f16x8 bh[2], bl[2];
      #pragma unroll
      for (int n=0;n<2;n++){
        const int fi = (((wn*2+n)*2 + kt)*64 + lane)*8;
        bh[n] = *(const f16x8*)(wb2h + fi);
        bl[n] = *(const f16x8*)(wb2l + fi);
      }
      #pragma unroll
      for (int m=0;m<4;m++){
        const int row = wm*64 + m*16 + lr;
        const int idx = (row*64 + kt*32 + lg*8) ^ swz;
        const f16x8 ah = *(const f16x8*)&AH1[idx];
        const f16x8 al = *(const f16x8*)&AL1[idx];
        #pragma unroll
        for (int n=0;n<2;n++){
          acc2[m][n] = __builtin_amdgcn_mfma_f32_16x16x32_f16(ah, bh[n], acc2[m][n], 0,0,0);
          acc2[m][n] = __builtin_amdgcn_mfma_f32_16x16x32_f16(ah, bl[n], acc2[m][n], 0,0,0);
          acc2[m][n] = __builtin_amdgcn_mfma_f32_16x16x32_f16(al, bh[n], acc2[m][n], 0,0,0);
        }
      }
    }
  }
  __syncthreads();   // all h1 reads complete before overlay write

  // h2 = relu(acc2 + b2): split hi/lo -> LDS
  {
    const float* b2 = ws + WS_B2F;
    #pragma unroll
    for (int n=0;n<2;n++){
      const int ch = wn*32 + n*16 + lr;
      const float b = b2[ch];
      #pragma unroll
      for (int m=0;m<4;m++){
        #pragma unroll
        for (int r=0;r<4;r++){
          const int row = wm*64 + m*16 + lg*4 + r;
          const float v = fmaxf(acc2[m][n][r] + b, 0.0f);
          const _Float16 hi = (_Float16)v;
          const _Float16 lo = (_Float16)(v - (float)hi);
          const int idx = (row*128 + ch) ^ ((row & 7) << 3);
          AH2[idx] = hi;
          AL2[idx] = lo;
        }
      }
    }
  }
  __syncthreads();

  // ---- layer 3 (128->128): M128 K128 N128, 3-term split MFMA
  f32x4 acc3[4][2];
  #pragma unroll
  for (int m=0;m<4;m++){
    #pragma unroll
    for (int n=0;n<2;n++) acc3[m][n] = (f32x4){0.f,0.f,0.f,0.f};
  }
  {
    const _Float16* wb3h = (const _Float16*)(ws + WS_WB3H);
    const _Float16* wb3l = (const _Float16*)(ws + WS_WB3L);
    const int swz = (lr & 7) << 3;
    #pragma unroll
    for (int kt=0; kt<4; kt++){
      f16x8 bh[2], bl[2];
      #pragma unroll
      for (int n=0;n<2;n++){
        const int fi = (((wn*2+n)*4 + kt)*64 + lane)*8;
        bh[n] = *(const f16x8*)(wb3h + fi);
        bl[n] = *(const f16x8*)(wb3l + fi);
      }
      #pragma unroll
      for (int m=0;m<4;m++){
        const int row = wm*64 + m*16 + lr;
        const int idx = (row*128 + kt*32 + lg*8) ^ swz;
        const f16x8 ah = *(const f16x8*)&AH2[idx];
        const f16x8 al = *(const f16x8*)&AL2[idx];
        #pragma unroll
        for (int n=0;n<2;n++){
          acc3[m][n] = __builtin_amdgcn_mfma_f32_16x16x32_f16(ah, bh[n], acc3[m][n], 0,0,0);
          acc3[m][n] = __builtin_amdgcn_mfma_f32_16x16x32_f16(ah, bl[n], acc3[m][n], 0,0,0);
          acc3[m][n] = __builtin_amdgcn_mfma_f32_16x16x32_f16(al, bh[n], acc3[m][n], 0,0,0);
        }
      }
    }
  }

  // epilogue: bias+relu, max over this wave's 64 rows, cross-group shfl, atomic
  {
    const float* b3 = ws + WS_B3F;
    #pragma unroll
    for (int n=0;n<2;n++){
      const int ch = wn*32 + n*16 + lr;
      const float b = b3[ch];
      float x = 0.0f;                        // relu floor
      #pragma unroll
      for (int m=0;m<4;m++){
        #pragma unroll
        for (int r=0;r<4;r++)
          x = fmaxf(x, acc3[m][n][r] + b);
      }
      x = fmaxf(x, __shfl_xor(x, 16, 64));
      x = fmaxf(x, __shfl_xor(x, 32, 64));
      if (lane < 16)
        atomicMax((unsigned*)(lat + cloud*128 + ch), __float_as_uint(x));
    }
  }
}

// ---------------- FPS v2: 1024 thr, 1 barrier/round, coords-in-LDS ------------
// Round publish/scan: each wave's best (v,i,x,y,z) -> double-buffered LDS slot;
// one barrier; every thread redundantly scans 16 slots (broadcast reads).
// Comparator (v2>v)||(v2==v&&i2<i) == jnp.argmax first-index semantics.
__device__ __forceinline__ void fps_round(int r, int t, int wv,
                                          float bv, int bi, float bx, float by, float bz,
                                          float (*cv)[16], int (*ci)[16],
                                          float (*cx)[16], float (*cy)[16], float (*cz)[16],
                                          float* ws, float* out, int cloud,
                                          float& s0, float& s1, float& s2){
  float v = bv; int i = bi;
  #pragma unroll
  for (int m=1;m<64;m<<=1){
    float v2=__shfl_xor(v,m,64); int i2=__shfl_xor(i,m,64);
    if (v2 > v || (v2 == v && i2 < i)){ v=v2; i=i2; }
  }
  const int p = r & 1;
  if ((i >> 4) == t){ cv[p][wv]=v; ci[p][wv]=i; cx[p][wv]=bx; cy[p][wv]=by; cz[p][wv]=bz; }
  __syncthreads();
  float wvv = cv[p][0]; int wi = ci[p][0]; int ws_slot = 0;
  #pragma unroll
  for (int e=1;e<16;e++){
    float v2=cv[p][e]; int i2=ci[p][e];
    if (v2 > wvv || (v2 == wvv && i2 < wi)){ wvv=v2; wi=i2; ws_slot=e; }
  }
  s0 = cx[p][ws_slot]; s1 = cy[p][ws_slot]; s2 = cz[p][ws_slot];
  if (t == 0){
    float* sw = ws + WS_SEL + cloud*48 + r*3;
    sw[0]=s0; sw[1]=s1; sw[2]=s2;
    size_t o = (cloud<B_) ? (size_t)(OUT_SRCKP + cloud*48 + r*3)
                          : (size_t)(OUT_TGTKP + (cloud-B_)*48 + r*3);
    out[o]=s0; out[o+1]=s1; out[o+2]=s2;
  }
}

__global__ __launch_bounds__(1024) void fps_kernel(const float* __restrict__ src,
                                                   const float* __restrict__ tgt,
                                                   const float* __restrict__ kw1,
                                                   const float* __restrict__ kb1,
                                                   const float* __restrict__ kw2,
                                                   const float* __restrict__ kb2,
                                                   float* ws, float* out){
  const int cloud = blockIdx.x; const int t = threadIdx.x;
  const int wv = t >> 6;
  const float* base = (cloud < B_) ? (src + (size_t)cloud*N_*3)
                                   : (tgt + (size_t)(cloud-B_)*N_*3);
  __shared__ float kpl[48];
  __shared__ float h[128];
  __shared__ float cv[2][16]; __shared__ int ci[2][16];
  __shared__ float cx[2][16]; __shared__ float cy[2][16]; __shared__ float cz[2][16];

  // 16 consecutive points/thread, 12 x float4 coalesced
  float px[16], py[16], pz[16];
  {
    const float4* b4 = (const float4*)(base + (size_t)t*48);
    float a[48];
    #pragma unroll
    for (int q=0;q<12;q++){ float4 v=b4[q]; a[q*4]=v.x; a[q*4+1]=v.y; a[q*4+2]=v.z; a[q*4+3]=v.w; }
    #pragma unroll
    for (int k=0;k<16;k++){ px[k]=a[k*3]; py[k]=a[k*3+1]; pz[k]=a[k*3+2]; }
  }

  // kp-MLP: kept serial (t<128 / t<48) for bit-identical kpl vs prior passing run
  const float* lat = ws + WS_LAT + cloud*128;
  if (t < 128){
    float acc = kb1[t];
    const float* w = kw1 + t*128;
    for (int c=0;c<128;c++) acc = fmaf(lat[c], w[c], acc);
    h[t] = fmaxf(acc, 0.0f);
  }
  __syncthreads();
  if (t < 48){
    float acc = kb2[t];
    const float* w = kw2 + t*128;
    for (int c=0;c<128;c++) acc = fmaf(h[c], w[c], acc);
    kpl[t] = acc;
  }
  __syncthreads();

  // dmin over 16 keypoints, j-outer (3 LDS broadcast reads per j)
  float mind[16];
  #pragma unroll
  for (int k=0;k<16;k++) mind[k] = 3.4028235e38f;
  for (int j=0;j<K_;j++){
    const float sx=kpl[j*3], sy=kpl[j*3+1], sz=kpl[j*3+2];
    #pragma unroll
    for (int k=0;k<16;k++)
      mind[k] = fminf(mind[k], dist2rn(px[k],py[k],pz[k], sx,sy,sz));
  }

  // round 0: argmax of keypoint-dmin
  float bv = -1.0f; int bi = 0; float bx=0.f, by=0.f, bz=0.f;
  #pragma unroll
  for (int k=0;k<16;k++){
    if (mind[k] > bv){ bv=mind[k]; bi=t*16+k; bx=px[k]; by=py[k]; bz=pz[k]; }
  }
  float s0, s1, s2;
  fps_round(0, t, wv, bv, bi, bx, by, bz, cv, ci, cx, cy, cz, ws, out, cloud, s0, s1, s2);

  // round 1: mind = dist to sel0 (REPLACE, matches reference)
  bv = -1.0f; bi = 0;
  #pragma unroll
  for (int k=0;k<16;k++){
    float d = dist2rn(px[k],py[k],pz[k], s0,s1,s2);
    mind[k] = d;
    if (d > bv){ bv=d; bi=t*16+k; bx=px[k]; by=py[k]; bz=pz[k]; }
  }
  fps_round(1, t, wv, bv, bi, bx, by, bz, cv, ci, cx, cy, cz, ws, out, cloud, s0, s1, s2);

  // rounds 2..15: mind = fmin(mind, dist to last sel)
  for (int r=2; r<K_; ++r){
    bv = -1.0f; bi = 0;
    #pragma unroll
    for (int k=0;k<16;k++){
      float d = dist2rn(px[k],py[k],pz[k], s0,s1,s2);
      float m = fminf(mind[k], d);
      mind[k] = m;
      if (m > bv){ bv=m; bi=t*16+k; bx=px[k]; by=py[k]; bz=pz[k]; }
    }
    fps_round(r, t, wv, bv, bi, bx, by, bz, cv, ci, cx, cy, cz, ws, out, cloud, s0, s1, s2);
  }
}

// ---------------- cage MLP + corner grid (64 blocks) --------------------------
__global__ void cage_mlp_kernel(const float* __restrict__ ws,
                                const float* __restrict__ cw1, const float* __restrict__ cb1,
                                const float* __restrict__ cw2, const float* __restrict__ cb2,
                                float* __restrict__ wsm){
  const int b = blockIdx.x >> 2, part = blockIdx.x & 3;
  const int t = threadIdx.x;
  __shared__ float diff[48]; __shared__ float h[128];
  if (t<48) diff[t] = __fsub_rn(ws[WS_SEL + (B_+b)*48 + t], ws[WS_SEL + b*48 + t]);
  __syncthreads();
  if (t<128){
    const float* w = cw1 + t*48;
    float acc = cb1[t];
    for (int j=0;j<48;j++) acc = fmaf(diff[j], w[j], acc);
    h[t] = fmaxf(acc, 0.0f);
  }
  __syncthreads();
  for (int o = part*384 + t; o < part*384 + 384; o += 256){
    const float* w = cw2 + o*128;
    float acc = cb2[o];
    for (int c=0;c<128;c++) acc = fmaf(h[c], w[c], acc);
    int flat = o/3, coord = o - flat*3;
    int u = flat>>6, v=(flat>>3)&7, z=flat&7;
    int g = (coord==0)?u:((coord==1)?v:z);
    float gv = (g==7)?1.0f:(float)g*(1.0f/7.0f);
    wsm[WS_CF + b*1536 + o] = gv + acc;
  }
}

// ---------------- trilinear cage deform ---------------------------------------
__global__ __launch_bounds__(256) void deform_kernel(const float* __restrict__ src,
                                                     const float* __restrict__ ws,
                                                     float* __restrict__ out){
  const int b = blockIdx.y;
  const int n = blockIdx.x*256 + threadIdx.x;
  __shared__ float cf[1536];
  for (int i=threadIdx.x;i<1536;i+=256) cf[i] = ws[WS_CF + b*1536 + i];
  __syncthreads();

  const float* p = src + ((size_t)b*N_ + n)*3;
  float pt[3]; int id[3]; float w[3];
  #pragma unroll
  for (int c=0;c<3;c++){
    float pv = p[c];
    float mn  = dec_ord(((const unsigned*)ws)[WS_PMIN+b*3+c]);
    float mxv = dec_ord(((const unsigned*)ws)[WS_PMAX+b*3+c]);
    float denom = __fadd_rn(__fsub_rn(mxv, mn), 1e-6f);
    float tc = __fmul_rn(__fdiv_rn(__fsub_rn(pv, mn), denom), 7.0f);
    int ic = (int)tc; ic = min(max(ic,0),6);
    pt[c]=pv; id[c]=ic; w[c]=__fsub_rn(tc, (float)ic);
  }
  const int flat = (id[0]<<6) + (id[1]<<3) + id[2];
  const float* c000 = cf + flat*3;
  const float wx=w[0], wy=w[1], wz=w[2];
  const float ux=__fsub_rn(1.0f,wx), uy=__fsub_rn(1.0f,wy), uz=__fsub_rn(1.0f,wz);
  const float w000=__fmul_rn(__fmul_rn(ux,uy),uz);
  const float w100=__fmul_rn(__fmul_rn(wx,uy),uz);
  const float w010=__fmul_rn(__fmul_rn(ux,wy),uz);
  const float w110=__fmul_rn(__fmul_rn(wx,wy),uz);
  const float w001=__fmul_rn(__fmul_rn(ux,uy),wz);
  const float w101=__fmul_rn(__fmul_rn(wx,uy),wz);
  const float w011=__fmul_rn(__fmul_rn(ux,wy),wz);
  const float w111=__fmul_rn(__fmul_rn(wx,wy),wz);
  #pragma unroll
  for (int c=0;c<3;c++){
    float d = __fmul_rn(w000, c000[c]);
    d = __fadd_rn(d, __fmul_rn(w100, c000[192+c]));
    d = __fadd_rn(d, __fmul_rn(w010, c000[24+c]));
    d = __fadd_rn(d, __fmul_rn(w110, c000[216+c]));
    d = __fadd_rn(d, __fmul_rn(w001, c000[3+c]));
    d = __fadd_rn(d, __fmul_rn(w101, c000[195+c]));
    d = __fadd_rn(d, __fmul_rn(w011, c000[27+c]));
    d = __fadd_rn(d, __fmul_rn(w111, c000[219+c]));
    out[((size_t)b*N_+n)*3 + c] = __fadd_rn(pt[c], d);
  }
}

// ---------------- launch ------------------------------------------------------
extern "C" void kernel_launch(void* const* d_in, const int* in_sizes, int n_in,
                              void* d_out, int out_size, void* d_ws, size_t ws_size,
                              hipStream_t stream){
  const float* src = (const float*)d_in[0];
  const float* tgt = (const float*)d_in[1];
  float* ws = (float*)d_ws;
  float* out = (float*)d_out;

  EncW ew;
  ew.w1 =(const float*)d_in[2];  ew.b1 =(const float*)d_in[3];
  ew.g1 =(const float*)d_in[4];  ew.be1=(const float*)d_in[5];
  ew.m1 =(const float*)d_in[6];  ew.v1 =(const float*)d_in[7];
  ew.w2 =(const float*)d_in[8];  ew.b2 =(const float*)d_in[9];
  ew.g2 =(const float*)d_in[10]; ew.be2=(const float*)d_in[11];
  ew.m2 =(const float*)d_in[12]; ew.v2 =(const float*)d_in[13];
  ew.w3 =(const float*)d_in[14]; ew.b3 =(const float*)d_in[15];
  ew.g3 =(const float*)d_in[16]; ew.be3=(const float*)d_in[17];
  ew.m3 =(const float*)d_in[18]; ew.v3 =(const float*)d_in[19];

  prep_kernel<<<128, 256, 0, stream>>>(ew, ws);
  minmax_kernel<<<dim3(8,16), 256, 0, stream>>>(src, ws);
  encode_kernel<<<dim3(128,32), 512, 0, stream>>>(src, tgt, ws, ws + WS_LAT);
  fps_kernel<<<32, 1024, 0, stream>>>(src, tgt,
      (const float*)d_in[20], (const float*)d_in[21],
      (const float*)d_in[22], (const float*)d_in[23], ws, out);
  cage_mlp_kernel<<<64, 256, 0, stream>>>(ws,
      (const float*)d_in[24], (const float*)d_in[25],
      (const float*)d_in[26], (const float*)d_in[27], ws);
  deform_kernel<<<dim3(64,16), 256, 0, stream>>>(src, ws, out);
}

// Round 3
// 319.323 us; speedup vs baseline: 1.0028x; 1.0028x over previous
//
#include <hip/hip_runtime.h>

#define B_ 16
#define N_ 16384
#define K_ 16

// ---- workspace layout (float offsets) ----
enum : int {
  WS_LAT  = 0,      // 32 x 128 latent (f32, atomicMax-as-uint, relu>=0)
  WS_SEL  = 5632,   // 32 x 48 selected keypoints
  WS_PMIN = 7168,   // 16 x 3 (ordered-uint encoded)
  WS_PMAX = 7216,   // 16 x 3 (ordered-uint encoded)
  WS_CF   = 7264,   // 16 x 512 x 3 cage corners
  WS_W1F  = 31840,  // 64 x 3  bn-folded (fp32)
  WS_B1F  = 32032,  // 64
  // split-f16 B-fragment tables (MFMA layout), built by prep:
  WS_WB2H = 32096,  // 8192 f16 (4096 floats): layer2 B hi frags [nt*2+kt][lane][8]
  WS_WB2L = 36192,  // 8192 f16
  WS_B2F  = 40288,  // 128 fp32 folded bias
  WS_WB3H = 40416,  // 32768 f16 (16384 floats): layer3 B hi frags [nt*4+kt][lane][8]
  WS_B3F  = 56800,  // 128 fp32 folded bias
  WS_WB3L = 56928,  // 32768 f16 (16384 floats)
  WS_END  = 73312
};

enum : int { OUT_DEF=0, OUT_SRCKP=786432, OUT_TGTKP=787200 };

typedef _Float16 f16x8 __attribute__((ext_vector_type(8)));
typedef _Float16 f16x2 __attribute__((ext_vector_type(2)));
typedef float    f32x4 __attribute__((ext_vector_type(4)));

__device__ __forceinline__ float dist2rn(float px,float py,float pz,float sx,float sy,float sz){
  float dx=__fsub_rn(px,sx), dy=__fsub_rn(py,sy), dz=__fsub_rn(pz,sz);
  return __fadd_rn(__fadd_rn(__fmul_rn(dx,dx),__fmul_rn(dy,dy)),__fmul_rn(dz,dz));
}

// ordered-uint encoding: monotone bijection float-order -> uint-order
__device__ __forceinline__ unsigned enc_ord(float x){
  unsigned u = __float_as_uint(x);
  return (u & 0x80000000u) ? ~u : (u | 0x80000000u);
}
__device__ __forceinline__ float dec_ord(unsigned e){
  return __uint_as_float((e & 0x80000000u) ? (e & 0x7fffffffu) : ~e);
}

// ---------------- prep: fold BN into encoder weights + split-f16 frags --------
struct EncW {
  const float *w1,*b1,*g1,*be1,*m1,*v1;
  const float *w2,*b2,*g2,*be2,*m2,*v2;
  const float *w3,*b3,*g3,*be3,*m3,*v3;
};

__device__ __forceinline__ float bn_scale(const float* g, const float* v, int ch){
  return g[ch] * (1.0f / sqrtf(v[ch] + 1e-5f));
}

__global__ void prep_kernel(EncW a, float* ws){
  const int stride = gridDim.x*blockDim.x;
  const int tid = blockIdx.x*blockDim.x + threadIdx.x;
  for (int i=tid;i<4096;i+=stride)            // zero latent (atomicMax target)
    ws[WS_LAT+i] = 0.0f;
  for (int i=tid;i<48;i+=stride){             // init min/max atomic targets
    ((unsigned*)ws)[WS_PMIN+i] = 0xFFFFFFFFu;
    ((unsigned*)ws)[WS_PMAX+i] = 0u;
  }
  for (int i=tid;i<192;i+=stride){            // W1F (fp32: layer1 stays on VALU)
    int o=i/3;
    ws[WS_W1F+i] = a.w1[i] * bn_scale(a.g1,a.v1,o);
  }
  for (int i=tid;i<64;i+=stride){             // B1F
    float s = bn_scale(a.g1,a.v1,i);
    ws[WS_B1F+i] = (a.b1[i] - a.m1[i])*s + a.be1[i];
  }
  // layer2 B-frags, split f16 hi/lo. frag layout: lane l of MFMA B operand holds
  // B[k = kt*32 + (l>>4)*8 + j][col = nt*16 + (l&15)], j=0..7 contiguous.
  for (int i=tid;i<8192;i+=stride){
    int j = i & 7, frag = i >> 3;
    int l = frag & 63, nk = frag >> 6;        // nk = nt*2 + kt
    int kt = nk & 1, nt = nk >> 1;
    int c = kt*32 + ((l>>4)<<3) + j;          // 0..63 in-channel (K)
    int o = nt*16 + (l&15);                   // 0..127 out-channel (N)
    float v = a.w2[o*64+c] * bn_scale(a.g2,a.v2,o);
    _Float16 h = (_Float16)v;
    ((_Float16*)(ws+WS_WB2H))[i] = h;
    ((_Float16*)(ws+WS_WB2L))[i] = (_Float16)(v - (float)h);
  }
  for (int i=tid;i<128;i+=stride){
    float s = bn_scale(a.g2,a.v2,i);
    ws[WS_B2F+i] = (a.b2[i] - a.m2[i])*s + a.be2[i];
  }
  // layer3 B-frags, split f16 hi/lo
  for (int i=tid;i<32768;i+=stride){
    int j = i & 7, frag = i >> 3;
    int l = frag & 63, nk = frag >> 6;        // nk = nt*4 + kt
    int kt = nk & 3, nt = nk >> 2;
    int c = kt*32 + ((l>>4)<<3) + j;          // 0..127 in-channel (K)
    int o = nt*16 + (l&15);                   // 0..127 out-channel (N)
    float v = a.w3[o*128+c] * bn_scale(a.g3,a.v3,o);
    _Float16 h = (_Float16)v;
    ((_Float16*)(ws+WS_WB3H))[i] = h;
    ((_Float16*)(ws+WS_WB3L))[i] = (_Float16)(v - (float)h);
  }
  for (int i=tid;i<128;i+=stride){
    float s = bn_scale(a.g3,a.v3,i);
    ws[WS_B3F+i] = (a.b3[i] - a.m3[i])*s + a.be3[i];
  }
}

// ---------------- source point min/max (exact, order-independent) -------------
__global__ __launch_bounds__(256) void minmax_kernel(const float* __restrict__ src,
                                                     float* __restrict__ ws){
  const int b = blockIdx.y, c = blockIdx.x, t = threadIdx.x;
  const float4* b4 = (const float4*)(src + (size_t)b*N_*3 + (size_t)c*2048*3 + (size_t)t*24);
  float a[24];
  #pragma unroll
  for (int q=0;q<6;q++){ float4 v=b4[q]; a[q*4]=v.x; a[q*4+1]=v.y; a[q*4+2]=v.z; a[q*4+3]=v.w; }
  float mn[3]={3.4e38f,3.4e38f,3.4e38f}, mx[3]={-3.4e38f,-3.4e38f,-3.4e38f};
  #pragma unroll
  for (int k=0;k<8;k++){
    mn[0]=fminf(mn[0],a[k*3  ]); mx[0]=fmaxf(mx[0],a[k*3  ]);
    mn[1]=fminf(mn[1],a[k*3+1]); mx[1]=fmaxf(mx[1],a[k*3+1]);
    mn[2]=fminf(mn[2],a[k*3+2]); mx[2]=fmaxf(mx[2],a[k*3+2]);
  }
  #pragma unroll
  for (int m=1;m<64;m<<=1){
    #pragma unroll
    for (int cc=0;cc<3;cc++){
      mn[cc]=fminf(mn[cc],__shfl_xor(mn[cc],m,64));
      mx[cc]=fmaxf(mx[cc],__shfl_xor(mx[cc],m,64));
    }
  }
  if ((t&63)==0){
    unsigned* wsu = (unsigned*)ws;
    #pragma unroll
    for (int cc=0;cc<3;cc++){
      atomicMin(&wsu[WS_PMIN + b*3 + cc], enc_ord(mn[cc]));
      atomicMax(&wsu[WS_PMAX + b*3 + cc], enc_ord(mx[cc]));
    }
  }
}

// ---------------- encoder v12: 64-pt tile, 256 thr, 32KB LDS ------------------
// R2 post-mortem: v11 at 39% occupancy (64KB LDS -> 2 blocks/CU), MfmaUtil 29%,
// VALUBusy 40% -> latency/barrier-bound, not pipe-bound. v12 halves the tile:
// 64 pts / 4 waves / 32KB LDS -> 5 blocks/CU (20 waves/CU). Per-output
// accumulation order (layer1 FMA chain, MFMA kt sequence, epilogue max order)
// is IDENTICAL to v11 -> bit-identical latent -> identical FPS selections.
__global__ __launch_bounds__(256, 4) void encode_kernel(const float* __restrict__ src,
                                                        const float* __restrict__ tgt,
                                                        const float* __restrict__ ws,
                                                        float* __restrict__ lat){
  const int cloud = blockIdx.y;
  const int tile  = blockIdx.x;              // 256 tiles/cloud, 64 pts each
  const int t = threadIdx.x;
  const int lane = t & 63;
  const int wn = __builtin_amdgcn_readfirstlane(t >> 6);   // 0..3 : cols 32*wn..+31
  const int lr = lane & 15;                  // row/col within 16x16 tile
  const int lg = lane >> 4;                  // k-group

  __shared__ alignas(16) _Float16 A[16384];  // 32KB
  _Float16* AH1 = A;                         // [64][64]  layer2 input hi
  _Float16* AL1 = A + 4096;                  //           layer2 input lo
  _Float16* AH2 = A;                         // [64][128] layer3 input hi (overlay)
  _Float16* AL2 = A + 8192;                  //           layer3 input lo

  const float* base = ((cloud < B_) ? (src + (size_t)cloud*N_*3)
                                    : (tgt + (size_t)(cloud-B_)*N_*3))
                      + (size_t)tile*64*3;

  // ---- layer 1 (3->64), fp32 VALU: thread t -> point t>>2, channels (t&3)*16..+15
  {
    const int pt = t >> 2, q = t & 3;        // pt 0..63
    const float x = base[pt*3+0], y = base[pt*3+1], z = base[pt*3+2];
    const float* w1 = ws + WS_W1F;
    const float* b1 = ws + WS_B1F;
    const int swz = (pt & 7) << 3;
    #pragma unroll
    for (int cc = 0; cc < 16; cc += 2){
      const int o = q*16 + cc;
      float v0 = fmaf(w1[o*3+2], z, fmaf(w1[o*3+1], y, w1[o*3+0]*x)) + b1[o];
      float v1 = fmaf(w1[o*3+5], z, fmaf(w1[o*3+4], y, w1[o*3+3]*x)) + b1[o+1];
      v0 = fmaxf(v0, 0.0f); v1 = fmaxf(v1, 0.0f);
      f16x2 h, l;
      h[0] = (_Float16)v0;              h[1] = (_Float16)v1;
      l[0] = (_Float16)(v0 - (float)h[0]); l[1] = (_Float16)(v1 - (float)h[1]);
      const int idx = (pt*64 + o) ^ swz;
      *(f16x2*)&AH1[idx] = h;
      *(f16x2*)&AL1[idx] = l;
    }
  }
  __syncthreads();

  // ---- layer 2 (64->128): M64 K64 N128, 3-term split MFMA
  f32x4 acc2[4][2];
  #pragma unroll
  for (int m=0;m<4;m++){
    #pragma unroll
    for (int n=0;n<2;n++) acc2[m][n] = (f32x4){0.f,0.f,0.f,0.f};
  }
  {
    const _Float16* wb2h = (const _Float16*)(ws + WS_WB2H);
    const _Float16* wb2l = (const _Float16*)(ws + WS_WB2L);
    const int swz = (lr & 7) << 3;
    #pragma unroll
    for (int kt=0; kt<2; kt++){
      f16x8 bh[2], bl[2];
      #pragma unroll
      for (int n=0;n<2;n++){
        const int fi = (((wn*2+n)*2 + kt)*64 + lane)*8;
        bh[n] = *(const f16x8*)(wb2h + fi);
        bl[n] = *(const f16x8*)(wb2l + fi);
      }
      #pragma unroll
      for (int m=0;m<4;m++){
        const int row = m*16 + lr;           // 0..63
        const int idx = (row*64 + kt*32 + lg*8) ^ swz;
        const f16x8 ah = *(const f16x8*)&AH1[idx];
        const f16x8 al = *(const f16x8*)&AL1[idx];
        #pragma unroll
        for (int n=0;n<2;n++){
          acc2[m][n] = __builtin_amdgcn_mfma_f32_16x16x32_f16(ah, bh[n], acc2[m][n], 0,0,0);
          acc2[m][n] = __builtin_amdgcn_mfma_f32_16x16x32_f16(ah, bl[n], acc2[m][n], 0,0,0);
          acc2[m][n] = __builtin_amdgcn_mfma_f32_16x16x32_f16(al, bh[n], acc2[m][n], 0,0,0);
        }
      }
    }
  }
  __syncthreads();   // all h1 reads complete before overlay write

  // h2 = relu(acc2 + b2): split hi/lo -> LDS
  {
    const float* b2 = ws + WS_B2F;
    #pragma unroll
    for (int n=0;n<2;n++){
      const int ch = wn*32 + n*16 + lr;
      const float b = b2[ch];
      #pragma unroll
      for (int m=0;m<4;m++){
        #pragma unroll
        for (int r=0;r<4;r++){
          const int row = m*16 + lg*4 + r;   // 0..63
          const float v = fmaxf(acc2[m][n][r] + b, 0.0f);
          const _Float16 hi = (_Float16)v;
          const _Float16 lo = (_Float16)(v - (float)hi);
          const int idx = (row*128 + ch) ^ ((row & 7) << 3);
          AH2[idx] = hi;
          AL2[idx] = lo;
        }
      }
    }
  }
  __syncthreads();

  // ---- layer 3 (128->128): M64 K128 N128, 3-term split MFMA
  f32x4 acc3[4][2];
  #pragma unroll
  for (int m=0;m<4;m++){
    #pragma unroll
    for (int n=0;n<2;n++) acc3[m][n] = (f32x4){0.f,0.f,0.f,0.f};
  }
  {
    const _Float16* wb3h = (const _Float16*)(ws + WS_WB3H);
    const _Float16* wb3l = (const _Float16*)(ws + WS_WB3L);
    const int swz = (lr & 7) << 3;
    #pragma unroll
    for (int kt=0; kt<4; kt++){
      f16x8 bh[2], bl[2];
      #pragma unroll
      for (int n=0;n<2;n++){
        const int fi = (((wn*2+n)*4 + kt)*64 + lane)*8;
        bh[n] = *(const f16x8*)(wb3h + fi);
        bl[n] = *(const f16x8*)(wb3l + fi);
      }
      #pragma unroll
      for (int m=0;m<4;m++){
        const int row = m*16 + lr;           // 0..63
        const int idx = (row*128 + kt*32 + lg*8) ^ swz;
        const f16x8 ah = *(const f16x8*)&AH2[idx];
        const f16x8 al = *(const f16x8*)&AL2[idx];
        #pragma unroll
        for (int n=0;n<2;n++){
          acc3[m][n] = __builtin_amdgcn_mfma_f32_16x16x32_f16(ah, bh[n], acc3[m][n], 0,0,0);
          acc3[m][n] = __builtin_amdgcn_mfma_f32_16x16x32_f16(ah, bl[n], acc3[m][n], 0,0,0);
          acc3[m][n] = __builtin_amdgcn_mfma_f32_16x16x32_f16(al, bh[n], acc3[m][n], 0,0,0);
        }
      }
    }
  }

  // epilogue: bias+relu, max over this wave's 64 rows, cross-group shfl, atomic
  {
    const float* b3 = ws + WS_B3F;
    #pragma unroll
    for (int n=0;n<2;n++){
      const int ch = wn*32 + n*16 + lr;
      const float b = b3[ch];
      float x = 0.0f;                        // relu floor
      #pragma unroll
      for (int m=0;m<4;m++){
        #pragma unroll
        for (int r=0;r<4;r++)
          x = fmaxf(x, acc3[m][n][r] + b);
      }
      x = fmaxf(x, __shfl_xor(x, 16, 64));
      x = fmaxf(x, __shfl_xor(x, 32, 64));
      if (lane < 16)
        atomicMax((unsigned*)(lat + cloud*128 + ch), __float_as_uint(x));
    }
  }
}

// ---------------- FPS v2: 1024 thr, 1 barrier/round, coords-in-LDS ------------
__device__ __forceinline__ void fps_round(int r, int t, int wv,
                                          float bv, int bi, float bx, float by, float bz,
                                          float (*cv)[16], int (*ci)[16],
                                          float (*cx)[16], float (*cy)[16], float (*cz)[16],
                                          float* ws, float* out, int cloud,
                                          float& s0, float& s1, float& s2){
  float v = bv; int i = bi;
  #pragma unroll
  for (int m=1;m<64;m<<=1){
    float v2=__shfl_xor(v,m,64); int i2=__shfl_xor(i,m,64);
    if (v2 > v || (v2 == v && i2 < i)){ v=v2; i=i2; }
  }
  const int p = r & 1;
  if ((i >> 4) == t){ cv[p][wv]=v; ci[p][wv]=i; cx[p][wv]=bx; cy[p][wv]=by; cz[p][wv]=bz; }
  __syncthreads();
  float wvv = cv[p][0]; int wi = ci[p][0]; int ws_slot = 0;
  #pragma unroll
  for (int e=1;e<16;e++){
    float v2=cv[p][e]; int i2=ci[p][e];
    if (v2 > wvv || (v2 == wvv && i2 < wi)){ wvv=v2; wi=i2; ws_slot=e; }
  }
  s0 = cx[p][ws_slot]; s1 = cy[p][ws_slot]; s2 = cz[p][ws_slot];
  if (t == 0){
    float* sw = ws + WS_SEL + cloud*48 + r*3;
    sw[0]=s0; sw[1]=s1; sw[2]=s2;
    size_t o = (cloud<B_) ? (size_t)(OUT_SRCKP + cloud*48 + r*3)
                          : (size_t)(OUT_TGTKP + (cloud-B_)*48 + r*3);
    out[o]=s0; out[o+1]=s1; out[o+2]=s2;
  }
}

__global__ __launch_bounds__(1024) void fps_kernel(const float* __restrict__ src,
                                                   const float* __restrict__ tgt,
                                                   const float* __restrict__ kw1,
                                                   const float* __restrict__ kb1,
                                                   const float* __restrict__ kw2,
                                                   const float* __restrict__ kb2,
                                                   float* ws, float* out){
  const int cloud = blockIdx.x; const int t = threadIdx.x;
  const int wv = t >> 6;
  const float* base = (cloud < B_) ? (src + (size_t)cloud*N_*3)
                                   : (tgt + (size_t)(cloud-B_)*N_*3);
  __shared__ float kpl[48];
  __shared__ float h[128];
  __shared__ float cv[2][16]; __shared__ int ci[2][16];
  __shared__ float cx[2][16]; __shared__ float cy[2][16]; __shared__ float cz[2][16];

  // 16 consecutive points/thread, 12 x float4 coalesced
  float px[16], py[16], pz[16];
  {
    const float4* b4 = (const float4*)(base + (size_t)t*48);
    float a[48];
    #pragma unroll
    for (int q=0;q<12;q++){ float4 v=b4[q]; a[q*4]=v.x; a[q*4+1]=v.y; a[q*4+2]=v.z; a[q*4+3]=v.w; }
    #pragma unroll
    for (int k=0;k<16;k++){ px[k]=a[k*3]; py[k]=a[k*3+1]; pz[k]=a[k*3+2]; }
  }

  // kp-MLP: kept serial (t<128 / t<48) for bit-identical kpl vs prior passing run
  const float* lat = ws + WS_LAT + cloud*128;
  if (t < 128){
    float acc = kb1[t];
    const float* w = kw1 + t*128;
    for (int c=0;c<128;c++) acc = fmaf(lat[c], w[c], acc);
    h[t] = fmaxf(acc, 0.0f);
  }
  __syncthreads();
  if (t < 48){
    float acc = kb2[t];
    const float* w = kw2 + t*128;
    for (int c=0;c<128;c++) acc = fmaf(h[c], w[c], acc);
    kpl[t] = acc;
  }
  __syncthreads();

  // dmin over 16 keypoints, j-outer (3 LDS broadcast reads per j)
  float mind[16];
  #pragma unroll
  for (int k=0;k<16;k++) mind[k] = 3.4028235e38f;
  for (int j=0;j<K_;j++){
    const float sx=kpl[j*3], sy=kpl[j*3+1], sz=kpl[j*3+2];
    #pragma unroll
    for (int k=0;k<16;k++)
      mind[k] = fminf(mind[k], dist2rn(px[k],py[k],pz[k], sx,sy,sz));
  }

  // round 0: argmax of keypoint-dmin
  float bv = -1.0f; int bi = 0; float bx=0.f, by=0.f, bz=0.f;
  #pragma unroll
  for (int k=0;k<16;k++){
    if (mind[k] > bv){ bv=mind[k]; bi=t*16+k; bx=px[k]; by=py[k]; bz=pz[k]; }
  }
  float s0, s1, s2;
  fps_round(0, t, wv, bv, bi, bx, by, bz, cv, ci, cx, cy, cz, ws, out, cloud, s0, s1, s2);

  // round 1: mind = dist to sel0 (REPLACE, matches reference)
  bv = -1.0f; bi = 0;
  #pragma unroll
  for (int k=0;k<16;k++){
    float d = dist2rn(px[k],py[k],pz[k], s0,s1,s2);
    mind[k] = d;
    if (d > bv){ bv=d; bi=t*16+k; bx=px[k]; by=py[k]; bz=pz[k]; }
  }
  fps_round(1, t, wv, bv, bi, bx, by, bz, cv, ci, cx, cy, cz, ws, out, cloud, s0, s1, s2);

  // rounds 2..15: mind = fmin(mind, dist to last sel)
  for (int r=2; r<K_; ++r){
    bv = -1.0f; bi = 0;
    #pragma unroll
    for (int k=0;k<16;k++){
      float d = dist2rn(px[k],py[k],pz[k], s0,s1,s2);
      float m = fminf(mind[k], d);
      mind[k] = m;
      if (m > bv){ bv=m; bi=t*16+k; bx=px[k]; by=py[k]; bz=pz[k]; }
    }
    fps_round(r, t, wv, bv, bi, bx, by, bz, cv, ci, cx, cy, cz, ws, out, cloud, s0, s1, s2);
  }
}

// ---------------- cage MLP + corner grid (64 blocks) --------------------------
__global__ void cage_mlp_kernel(const float* __restrict__ ws,
                                const float* __restrict__ cw1, const float* __restrict__ cb1,
                                const float* __restrict__ cw2, const float* __restrict__ cb2,
                                float* __restrict__ wsm){
  const int b = blockIdx.x >> 2, part = blockIdx.x & 3;
  const int t = threadIdx.x;
  __shared__ float diff[48]; __shared__ float h[128];
  if (t<48) diff[t] = __fsub_rn(ws[WS_SEL + (B_+b)*48 + t], ws[WS_SEL + b*48 + t]);
  __syncthreads();
  if (t<128){
    const float* w = cw1 + t*48;
    float acc = cb1[t];
    for (int j=0;j<48;j++) acc = fmaf(diff[j], w[j], acc);
    h[t] = fmaxf(acc, 0.0f);
  }
  __syncthreads();
  for (int o = part*384 + t; o < part*384 + 384; o += 256){
    const float* w = cw2 + o*128;
    float acc = cb2[o];
    for (int c=0;c<128;c++) acc = fmaf(h[c], w[c], acc);
    int flat = o/3, coord = o - flat*3;
    int u = flat>>6, v=(flat>>3)&7, z=flat&7;
    int g = (coord==0)?u:((coord==1)?v:z);
    float gv = (g==7)?1.0f:(float)g*(1.0f/7.0f);
    wsm[WS_CF + b*1536 + o] = gv + acc;
  }
}

// ---------------- trilinear cage deform ---------------------------------------
__global__ __launch_bounds__(256) void deform_kernel(const float* __restrict__ src,
                                                     const float* __restrict__ ws,
                                                     float* __restrict__ out){
  const int b = blockIdx.y;
  const int n = blockIdx.x*256 + threadIdx.x;
  __shared__ float cf[1536];
  for (int i=threadIdx.x;i<1536;i+=256) cf[i] = ws[WS_CF + b*1536 + i];
  __syncthreads();

  const float* p = src + ((size_t)b*N_ + n)*3;
  float pt[3]; int id[3]; float w[3];
  #pragma unroll
  for (int c=0;c<3;c++){
    float pv = p[c];
    float mn  = dec_ord(((const unsigned*)ws)[WS_PMIN+b*3+c]);
    float mxv = dec_ord(((const unsigned*)ws)[WS_PMAX+b*3+c]);
    float denom = __fadd_rn(__fsub_rn(mxv, mn), 1e-6f);
    float tc = __fmul_rn(__fdiv_rn(__fsub_rn(pv, mn), denom), 7.0f);
    int ic = (int)tc; ic = min(max(ic,0),6);
    pt[c]=pv; id[c]=ic; w[c]=__fsub_rn(tc, (float)ic);
  }
  const int flat = (id[0]<<6) + (id[1]<<3) + id[2];
  const float* c000 = cf + flat*3;
  const float wx=w[0], wy=w[1], wz=w[2];
  const float ux=__fsub_rn(1.0f,wx), uy=__fsub_rn(1.0f,wy), uz=__fsub_rn(1.0f,wz);
  const float w000=__fmul_rn(__fmul_rn(ux,uy),uz);
  const float w100=__fmul_rn(__fmul_rn(wx,uy),uz);
  const float w010=__fmul_rn(__fmul_rn(ux,wy),uz);
  const float w110=__fmul_rn(__fmul_rn(wx,wy),uz);
  const float w001=__fmul_rn(__fmul_rn(ux,uy),wz);
  const float w101=__fmul_rn(__fmul_rn(wx,uy),wz);
  const float w011=__fmul_rn(__fmul_rn(ux,wy),wz);
  const float w111=__fmul_rn(__fmul_rn(wx,wy),wz);
  #pragma unroll
  for (int c=0;c<3;c++){
    float d = __fmul_rn(w000, c000[c]);
    d = __fadd_rn(d, __fmul_rn(w100, c000[192+c]));
    d = __fadd_rn(d, __fmul_rn(w010, c000[24+c]));
    d = __fadd_rn(d, __fmul_rn(w110, c000[216+c]));
    d = __fadd_rn(d, __fmul_rn(w001, c000[3+c]));
    d = __fadd_rn(d, __fmul_rn(w101, c000[195+c]));
    d = __fadd_rn(d, __fmul_rn(w011, c000[27+c]));
    d = __fadd_rn(d, __fmul_rn(w111, c000[219+c]));
    out[((size_t)b*N_+n)*3 + c] = __fadd_rn(pt[c], d);
  }
}

// ---------------- launch ------------------------------------------------------
extern "C" void kernel_launch(void* const* d_in, const int* in_sizes, int n_in,
                              void* d_out, int out_size, void* d_ws, size_t ws_size,
                              hipStream_t stream){
  const float* src = (const float*)d_in[0];
  const float* tgt = (const float*)d_in[1];
  float* ws = (float*)d_ws;
  float* out = (float*)d_out;

  EncW ew;
  ew.w1 =(const float*)d_in[2];  ew.b1 =(const float*)d_in[3];
  ew.g1 =(const float*)d_in[4];  ew.be1=(const float*)d_in[5];
  ew.m1 =(const float*)d_in[6];  ew.v1 =(const float*)d_in[7];
  ew.w2 =(const float*)d_in[8];  ew.b2 =(const float*)d_in[9];
  ew.g2 =(const float*)d_in[10]; ew.be2=(const float*)d_in[11];
  ew.m2 =(const float*)d_in[12]; ew.v2 =(const float*)d_in[13];
  ew.w3 =(const float*)d_in[14]; ew.b3 =(const float*)d_in[15];
  ew.g3 =(const float*)d_in[16]; ew.be3=(const float*)d_in[17];
  ew.m3 =(const float*)d_in[18]; ew.v3 =(const float*)d_in[19];

  prep_kernel<<<128, 256, 0, stream>>>(ew, ws);
  minmax_kernel<<<dim3(8,16), 256, 0, stream>>>(src, ws);
  encode_kernel<<<dim3(256,32), 256, 0, stream>>>(src, tgt, ws, ws + WS_LAT);
  fps_kernel<<<32, 1024, 0, stream>>>(src, tgt,
      (const float*)d_in[20], (const float*)d_in[21],
      (const float*)d_in[22], (const float*)d_in[23], ws, out);
  cage_mlp_kernel<<<64, 256, 0, stream>>>(ws,
      (const float*)d_in[24], (const float*)d_in[25],
      (const float*)d_in[26], (const float*)d_in[27], ws);
  deform_kernel<<<dim3(64,16), 256, 0, stream>>>(src, ws, out);
}